// Round 2
// baseline (1362.403 us; speedup 1.0000x reference)
//
#include <hip/hip_runtime.h>
#include <stdint.h>

// Problem constants
#define LL 128
#define BB 4096
#define DD 300
#define DP 320              // K padded to multiple of 32
#define SROW 328            // LDS row stride in bf16 elements (>= DP, bank advance 4 dwords)
#define OWN 64              // rows owned per block
#define ROWS 66             // staged rows: base-1 .. base+64 (halo both sides)

typedef __attribute__((ext_vector_type(8))) short short8;
typedef __attribute__((ext_vector_type(4))) float f32x4;

static constexpr int S16_ELEMS = ROWS * SROW;
// S16 (bf16) + q1s[64] + q2s[65] + w0s/w1s/w2s[64 each]
static constexpr int SMEM_BYTES = S16_ELEMS * 2 + (64 + 65 + 64 + 64 + 64) * 4;

__device__ __forceinline__ unsigned short f2bf(float f) {
    unsigned int u = __builtin_bit_cast(unsigned int, f);
    u = (u + 0x7fffu + ((u >> 16) & 1u)) >> 16;   // RNE
    return (unsigned short)u;
}
__device__ __forceinline__ float bf2f(unsigned short h) {
    unsigned int u = ((unsigned int)h) << 16;
    return __builtin_bit_cast(float, u);
}

// ---- prep: Wb[320][320] = bf16( 0.5*(W + W^T) ), zero padded ----
__global__ void prep_w_kernel(const float* __restrict__ W, unsigned short* __restrict__ Wb) {
    int i = blockIdx.x * 256 + threadIdx.x;
    if (i >= DP * DP) return;
    int r = i / DP, c = i % DP;
    float v = 0.0f;
    if (r < DD && c < DD) v = 0.5f * (W[r * DD + c] + W[c * DD + r]);
    Wb[i] = f2bf(v);
}

// ---- fused, L-split: each block owns 64 rows of one b; 3 blocks/CU ----
__global__ __launch_bounds__(512, 6) void fused_kernel(
        const float* __restrict__ sent, const int* __restrict__ sizes,
        const unsigned short* __restrict__ Wb, float* __restrict__ out) {
    extern __shared__ char smem[];
    unsigned short* S16 = (unsigned short*)smem;
    float* q1s = (float*)(smem + S16_ELEMS * 2);  // [64]  q1 for l_local 0..63
    float* q2s = q1s + 64;                        // [65]  q2 for global l = base-1+i
    float* w0s = q2s + 65;
    float* w1s = w0s + 64;
    float* w2s = w1s + 64;

    const int bid = blockIdx.x;
    const int b = bid >> 1;
    const int base = (bid & 1) * OWN;
    const int t = threadIdx.x;

    // ---------------- stage rows base-1 .. base+64 as bf16 (zeros out of range) ----------------
    for (int idx = t; idx < ROWS * 75; idx += 512) {
        const int r = idx / 75, c4 = idx % 75;
        const int g = base - 1 + r;               // global row
        ushort4 h; h.x = 0; h.y = 0; h.z = 0; h.w = 0;
        if (g >= 0 && g < LL) {
            const float4 v = ((const float4*)(sent + ((size_t)g * BB + b) * DD))[c4];
            h.x = f2bf(v.x); h.y = f2bf(v.y); h.z = f2bf(v.z); h.w = f2bf(v.w);
        }
        *(ushort4*)&S16[r * SROW + c4 * 4] = h;
    }
    // zero pad cols 300..327 (7 ushort4 per row)
    for (int idx = t; idx < ROWS * 7; idx += 512) {
        const int r = idx / 7, c = 300 + (idx % 7) * 4;
        ushort4 z; z.x = 0; z.y = 0; z.z = 0; z.w = 0;
        *(ushort4*)&S16[r * SROW + c] = z;
    }
    // zero score accumulators (q1s[64] + q2s[65] contiguous = 129 floats)
    if (t < 129) q1s[t] = 0.0f;
    __syncthreads();

    // ---------------- MFMA: Yt = Wsym * S_owned^T (rows d=0..319, cols l_local=0..63) ----------
    const int lane = t & 63;
    const int wave = t >> 6;       // 0..7
    const int mw = wave & 3;       // 0..3 : d partition (80 rows each)
    const int nw2 = wave >> 2;     // 0..1 : l partition (32 cols each)
    const int lo = lane & 15;
    const int quad = lane >> 4;

    f32x4 acc[5][2];
    #pragma unroll
    for (int i = 0; i < 5; i++)
        #pragma unroll
        for (int j = 0; j < 2; j++)
            acc[i][j] = (f32x4){0.f, 0.f, 0.f, 0.f};

    #pragma unroll
    for (int kc = 0; kc < 10; kc++) {
        short8 Bf[2];
        #pragma unroll
        for (int j = 0; j < 2; j++)
            Bf[j] = *(const short8*)&S16[(1 + 16 * (2 * nw2 + j) + lo) * SROW + kc * 32 + quad * 8];
        #pragma unroll
        for (int i = 0; i < 5; i++) {
            const short8 Af = *(const short8*)&Wb[(16 * (5 * mw + i) + lo) * DP + kc * 32 + quad * 8];
            #pragma unroll
            for (int j = 0; j < 2; j++)
                acc[i][j] = __builtin_amdgcn_mfma_f32_16x16x32_bf16(Af, Bf[j], acc[i][j], 0, 0, 0);
        }
    }

    // ---------------- dots ----------------
    // lane holds cols l_local = 16*(2*nw2+j)+lo, rows d = 16*(5*mw+i)+quad*4+r
    // q1[l] = Yt[:,l].s_l   (LDS row l+1);  q2[l] = Yt[:,l].s_{l+1}  (LDS row l+2)
    // qm = q2[base-1] = Yt[:,0].s_{base-1}  (LDS row 0; valid only in lo==0,nw2==0 lanes)
    float q1v[2] = {0.f, 0.f};
    float q2v[2] = {0.f, 0.f};
    float qm = 0.f;
    #pragma unroll
    for (int i = 0; i < 5; i++) {
        const int d0 = 16 * (5 * mw + i) + quad * 4;
        const ushort4 s0 = *(const ushort4*)&S16[d0];  // row 0 (broadcast across lo)
        const f32x4 a0 = acc[i][0];
        qm += a0[0] * bf2f(s0.x) + a0[1] * bf2f(s0.y) + a0[2] * bf2f(s0.z) + a0[3] * bf2f(s0.w);
        #pragma unroll
        for (int j = 0; j < 2; j++) {
            const int ll = 16 * (2 * nw2 + j) + lo;
            const ushort4 s1 = *(const ushort4*)&S16[(ll + 1) * SROW + d0];
            const ushort4 s2 = *(const ushort4*)&S16[(ll + 2) * SROW + d0];
            const f32x4 a = acc[i][j];
            q1v[j] += a[0] * bf2f(s1.x) + a[1] * bf2f(s1.y) + a[2] * bf2f(s1.z) + a[3] * bf2f(s1.w);
            q2v[j] += a[0] * bf2f(s2.x) + a[1] * bf2f(s2.y) + a[2] * bf2f(s2.z) + a[3] * bf2f(s2.w);
        }
    }
    // reduce across quads (lanes lo, lo+16, lo+32, lo+48), then atomic across mw waves
    #pragma unroll
    for (int j = 0; j < 2; j++) {
        float v1 = q1v[j], v2 = q2v[j];
        v1 += __shfl_xor(v1, 16); v1 += __shfl_xor(v1, 32);
        v2 += __shfl_xor(v2, 16); v2 += __shfl_xor(v2, 32);
        if (quad == 0) {
            const int ll = 16 * (2 * nw2 + j) + lo;
            atomicAdd(&q1s[ll], v1);
            atomicAdd(&q2s[ll + 1], v2);
        }
    }
    qm += __shfl_xor(qm, 16); qm += __shfl_xor(qm, 32);
    if (lane == 0 && nw2 == 0) atomicAdd(&q2s[0], qm);
    __syncthreads();

    // ---------------- softmax weights, once per owned l ----------------
    const int sz = sizes[b];
    if (t < OWN) {
        const int l = base + t;
        const float inv_d = 1.0f / 300.0f;
        const float NEG_INF = -__builtin_inff();
        const float a1 = q1s[t] * inv_d;
        const float a0 = (l >= 1 && l < sz) ? q2s[t] * inv_d : NEG_INF;
        const float a2 = (l < LL - 1 && l < sz - 1) ? q2s[t + 1] * inv_d : NEG_INF;
        const float mx = fmaxf(a1, fmaxf(a0, a2));
        const float e0 = __expf(a0 - mx);
        const float e1 = __expf(a1 - mx);
        const float e2 = __expf(a2 - mx);
        const float inv = 1.0f / (e0 + e1 + e2);
        w0s[t] = e0 * inv;
        w1s[t] = e1 * inv;
        w2s[t] = e2 * inv;
    }
    __syncthreads();

    // ---------------- combine: all 512 threads over (l_local, d/4), float4 stores --------------
    for (int idx = t; idx < OWN * 75; idx += 512) {
        const int ll = idx / 75;
        const int d = (idx % 75) * 4;
        const float W0 = w0s[ll], W1 = w1s[ll], W2 = w2s[ll];
        const ushort4 sp = *(const ushort4*)&S16[ll * SROW + d];        // s_{l-1} (row 0 zeroed at base=0)
        const ushort4 sc = *(const ushort4*)&S16[(ll + 1) * SROW + d];  // s_l
        const ushort4 sn = *(const ushort4*)&S16[(ll + 2) * SROW + d];  // s_{l+1} (top zeroed)
        float4 o;
        o.x = W1 * bf2f(sc.x) + W0 * bf2f(sp.x) + W2 * bf2f(sn.x);
        o.y = W1 * bf2f(sc.y) + W0 * bf2f(sp.y) + W2 * bf2f(sn.y);
        o.z = W1 * bf2f(sc.z) + W0 * bf2f(sp.z) + W2 * bf2f(sn.z);
        o.w = W1 * bf2f(sc.w) + W0 * bf2f(sp.w) + W2 * bf2f(sn.w);
        *(float4*)&out[((size_t)(base + ll) * BB + b) * DD + d] = o;
    }
}

extern "C" void kernel_launch(void* const* d_in, const int* in_sizes, int n_in,
                              void* d_out, int out_size, void* d_ws, size_t ws_size,
                              hipStream_t stream) {
    const float* sent = (const float*)d_in[0];
    const int* sizes  = (const int*)d_in[1];
    const float* W    = (const float*)d_in[2];
    float* out        = (float*)d_out;
    unsigned short* Wb = (unsigned short*)d_ws;   // 320*320*2 = 204800 B

    prep_w_kernel<<<(DP * DP + 255) / 256, 256, 0, stream>>>(W, Wb);

    hipFuncSetAttribute(reinterpret_cast<const void*>(fused_kernel),
                        hipFuncAttributeMaxDynamicSharedMemorySize, SMEM_BYTES);
    fused_kernel<<<BB * 2, 512, SMEM_BYTES, stream>>>(sent, sizes, Wb, out);
}

// Round 5
// 1180.018 us; speedup vs baseline: 1.1546x; 1.1546x over previous
//
#include <hip/hip_runtime.h>
#include <stdint.h>

// Problem constants
#define LL 128
#define BB 4096
#define DD 300
#define DP 320              // K padded to multiple of 32
#define SROW 328            // LDS row stride in bf16 elements (>= DP, bank advance 4 dwords)
#define OWN 64              // rows owned per block
#define ROWS 66             // staged rows: base-1 .. base+64 (halo both sides)

typedef __attribute__((ext_vector_type(8))) short short8;
typedef __attribute__((ext_vector_type(4))) float f32x4;

static constexpr int S16_ELEMS = ROWS * SROW;
// S16 (bf16) + q1s[64] + q2s[65] + w0s/w1s/w2s[64 each]
static constexpr int SMEM_BYTES = S16_ELEMS * 2 + (64 + 65 + 64 + 64 + 64) * 4;

__device__ __forceinline__ unsigned short f2bf(float f) {
    unsigned int u = __builtin_bit_cast(unsigned int, f);
    u = (u + 0x7fffu + ((u >> 16) & 1u)) >> 16;   // RNE
    return (unsigned short)u;
}
__device__ __forceinline__ float bf2f(unsigned short h) {
    unsigned int u = ((unsigned int)h) << 16;
    return __builtin_bit_cast(float, u);
}

// ---- prep: Wf = bf16( 0.5*(W + W^T) ) in MFMA fragment order ----
// Wf[((kc*20 + mt)*64 + lane)*8 + e] = Wsym[16*mt + (lane&15)][kc*32 + (lane>>4)*8 + e]
// so each wave's (kc, mt) A-fragment load is one contiguous 1KB transaction.
__global__ void prep_w_kernel(const float* __restrict__ W, unsigned short* __restrict__ Wf) {
    int i = blockIdx.x * 256 + threadIdx.x;
    if (i >= DP * DP) return;
    const int e = i & 7;
    const int lane = (i >> 3) & 63;
    const int idx = i >> 9;            // kc*20 + mt, 0..199
    const int kc = idx / 20, mt = idx % 20;
    const int r = 16 * mt + (lane & 15);
    const int c = kc * 32 + (lane >> 4) * 8 + e;
    float v = 0.0f;
    if (r < DD && c < DD) v = 0.5f * (W[r * DD + c] + W[c * DD + r]);
    Wf[i] = f2bf(v);
}

// ---- fused, L-split: each block owns 64 rows of one b ----
__global__ __launch_bounds__(512) void fused_kernel(
        const float* __restrict__ sent, const int* __restrict__ sizes,
        const unsigned short* __restrict__ Wf, float* __restrict__ out) {
    extern __shared__ char smem[];
    unsigned short* S16 = (unsigned short*)smem;
    float* q1s = (float*)(smem + S16_ELEMS * 2);  // [64]  q1 for l_local 0..63
    float* q2s = q1s + 64;                        // [65]  q2 for global l = base-1+i
    float* w0s = q2s + 65;
    float* w1s = w0s + 64;
    float* w2s = w1s + 64;

    const int bid = blockIdx.x;
    const int b = bid >> 1;
    const int base = (bid & 1) * OWN;
    const int t = threadIdx.x;

    // ---------------- stage rows base-1 .. base+64 as bf16 (zeros out of range) ----------------
    for (int idx = t; idx < ROWS * 75; idx += 512) {
        const int r = idx / 75, c4 = idx % 75;
        const int g = base - 1 + r;               // global row
        ushort4 h; h.x = 0; h.y = 0; h.z = 0; h.w = 0;
        if (g >= 0 && g < LL) {
            const float4 v = ((const float4*)(sent + ((size_t)g * BB + b) * DD))[c4];
            h.x = f2bf(v.x); h.y = f2bf(v.y); h.z = f2bf(v.z); h.w = f2bf(v.w);
        }
        *(ushort4*)&S16[r * SROW + c4 * 4] = h;
    }
    // zero pad cols 300..327 (7 ushort4 per row)
    for (int idx = t; idx < ROWS * 7; idx += 512) {
        const int r = idx / 7, c = 300 + (idx % 7) * 4;
        ushort4 z; z.x = 0; z.y = 0; z.z = 0; z.w = 0;
        *(ushort4*)&S16[r * SROW + c] = z;
    }
    // zero score accumulators (q1s[64] + q2s[65] contiguous = 129 floats)
    if (t < 129) q1s[t] = 0.0f;
    __syncthreads();

    // ---------------- MFMA: Yt = Wsym * S_owned^T (rows d=0..319, cols l_local=0..63) ----------
    const int lane = t & 63;
    const int wave = t >> 6;       // 0..7
    const int mw = wave & 3;       // 0..3 : d partition (80 rows each)
    const int nw2 = wave >> 2;     // 0..1 : l partition (32 cols each)
    const int lo = lane & 15;
    const int quad = lane >> 4;

    f32x4 acc[5][2];
    #pragma unroll
    for (int i = 0; i < 5; i++)
        #pragma unroll
        for (int j = 0; j < 2; j++)
            acc[i][j] = (f32x4){0.f, 0.f, 0.f, 0.f};

    // fragment-ordered base for this wave: fragments (kc, 5*mw + i)
    const unsigned short* Wbase = Wf + ((size_t)(5 * mw) * 64 + lane) * 8;

    #pragma unroll
    for (int kc = 0; kc < 10; kc++) {
        short8 Bf[2];
        #pragma unroll
        for (int j = 0; j < 2; j++)
            Bf[j] = *(const short8*)&S16[(1 + 16 * (2 * nw2 + j) + lo) * SROW + kc * 32 + quad * 8];
        #pragma unroll
        for (int i = 0; i < 5; i++) {
            const short8 Af = *(const short8*)&Wbase[((size_t)(kc * 20 + i) * 64) * 8];
            #pragma unroll
            for (int j = 0; j < 2; j++)
                acc[i][j] = __builtin_amdgcn_mfma_f32_16x16x32_bf16(Af, Bf[j], acc[i][j], 0, 0, 0);
        }
    }

    // ---------------- dots ----------------
    // lane holds cols l_local = 16*(2*nw2+j)+lo, rows d = 16*(5*mw+i)+quad*4+r
    // q1[l] = Yt[:,l].s_l   (LDS row l+1);  q2[l] = Yt[:,l].s_{l+1}  (LDS row l+2)
    // qm = q2[base-1] = Yt[:,0].s_{base-1}  (LDS row 0)
    float q1v[2] = {0.f, 0.f};
    float q2v[2] = {0.f, 0.f};
    float qm = 0.f;
    #pragma unroll
    for (int i = 0; i < 5; i++) {
        const int d0 = 16 * (5 * mw + i) + quad * 4;
        const ushort4 s0 = *(const ushort4*)&S16[d0];  // row 0 (broadcast across lo)
        const f32x4 a0 = acc[i][0];
        qm += a0[0] * bf2f(s0.x) + a0[1] * bf2f(s0.y) + a0[2] * bf2f(s0.z) + a0[3] * bf2f(s0.w);
        #pragma unroll
        for (int j = 0; j < 2; j++) {
            const int ll = 16 * (2 * nw2 + j) + lo;
            const ushort4 s1 = *(const ushort4*)&S16[(ll + 1) * SROW + d0];
            const ushort4 s2 = *(const ushort4*)&S16[(ll + 2) * SROW + d0];
            const f32x4 a = acc[i][j];
            q1v[j] += a[0] * bf2f(s1.x) + a[1] * bf2f(s1.y) + a[2] * bf2f(s1.z) + a[3] * bf2f(s1.w);
            q2v[j] += a[0] * bf2f(s2.x) + a[1] * bf2f(s2.y) + a[2] * bf2f(s2.z) + a[3] * bf2f(s2.w);
        }
    }
    // reduce across quads (lanes lo, lo+16, lo+32, lo+48), then atomic across mw waves
    #pragma unroll
    for (int j = 0; j < 2; j++) {
        float v1 = q1v[j], v2 = q2v[j];
        v1 += __shfl_xor(v1, 16); v1 += __shfl_xor(v1, 32);
        v2 += __shfl_xor(v2, 16); v2 += __shfl_xor(v2, 32);
        if (quad == 0) {
            const int ll = 16 * (2 * nw2 + j) + lo;
            atomicAdd(&q1s[ll], v1);
            atomicAdd(&q2s[ll + 1], v2);
        }
    }
    qm += __shfl_xor(qm, 16); qm += __shfl_xor(qm, 32);
    if (lane == 0 && nw2 == 0) atomicAdd(&q2s[0], qm);
    __syncthreads();

    // ---------------- softmax weights, once per owned l ----------------
    const int sz = sizes[b];
    if (t < OWN) {
        const int l = base + t;
        const float inv_d = 1.0f / 300.0f;
        const float NEG_INF = -__builtin_inff();
        const float a1 = q1s[t] * inv_d;
        const float a0 = (l >= 1 && l < sz) ? q2s[t] * inv_d : NEG_INF;
        const float a2 = (l < LL - 1 && l < sz - 1) ? q2s[t + 1] * inv_d : NEG_INF;
        const float mx = fmaxf(a1, fmaxf(a0, a2));
        const float e0 = __expf(a0 - mx);
        const float e1 = __expf(a1 - mx);
        const float e2 = __expf(a2 - mx);
        const float inv = 1.0f / (e0 + e1 + e2);
        w0s[t] = e0 * inv;
        w1s[t] = e1 * inv;
        w2s[t] = e2 * inv;
    }
    __syncthreads();

    // ---------------- combine: all 512 threads over (l_local, d/4), float4 stores --------------
    for (int idx = t; idx < OWN * 75; idx += 512) {
        const int ll = idx / 75;
        const int d = (idx % 75) * 4;
        const float W0 = w0s[ll], W1 = w1s[ll], W2 = w2s[ll];
        const ushort4 sp = *(const ushort4*)&S16[ll * SROW + d];        // s_{l-1} (row 0 zeroed at base=0)
        const ushort4 sc = *(const ushort4*)&S16[(ll + 1) * SROW + d];  // s_l
        const ushort4 sn = *(const ushort4*)&S16[(ll + 2) * SROW + d];  // s_{l+1} (top zeroed)
        float4 o;
        o.x = W1 * bf2f(sc.x) + W0 * bf2f(sp.x) + W2 * bf2f(sn.x);
        o.y = W1 * bf2f(sc.y) + W0 * bf2f(sp.y) + W2 * bf2f(sn.y);
        o.z = W1 * bf2f(sc.z) + W0 * bf2f(sp.z) + W2 * bf2f(sn.z);
        o.w = W1 * bf2f(sc.w) + W0 * bf2f(sp.w) + W2 * bf2f(sn.w);
        *(float4*)&out[((size_t)(base + ll) * BB + b) * DD + d] = o;
    }
}

extern "C" void kernel_launch(void* const* d_in, const int* in_sizes, int n_in,
                              void* d_out, int out_size, void* d_ws, size_t ws_size,
                              hipStream_t stream) {
    const float* sent = (const float*)d_in[0];
    const int* sizes  = (const int*)d_in[1];
    const float* W    = (const float*)d_in[2];
    float* out        = (float*)d_out;
    unsigned short* Wf = (unsigned short*)d_ws;   // 320*320*2 = 204800 B, fragment order

    prep_w_kernel<<<(DP * DP + 255) / 256, 256, 0, stream>>>(W, Wf);

    hipFuncSetAttribute(reinterpret_cast<const void*>(fused_kernel),
                        hipFuncAttributeMaxDynamicSharedMemorySize, SMEM_BYTES);
    fused_kernel<<<BB * 2, 512, SMEM_BYTES, stream>>>(sent, sizes, Wf, out);
}